// Round 3
// baseline (236.358 us; speedup 1.0000x reference)
//
#include <hip/hip_runtime.h>

#define LAMBDA_COORD 5.0f
#define LAMBDA_NOOBJ 0.5f
#define DD 30
#define BLOCK 64    // one wave per block
#define CELLS 64    // cells per chunk
#define ITERS 4     // chunks per block -> grid 3136
#define F4C (CELLS * DD / 4)   // 480 float4 per input per chunk

__device__ __forceinline__ float iou_t(float tx, float ty, float tw, float th,
                                       float px, float py, float pw, float ph) {
    float xl = fmaxf(tx - tw * 0.5f, px - pw * 0.5f);
    float yt = fmaxf(ty - th * 0.5f, py - ph * 0.5f);
    float xr = fminf(tx + tw * 0.5f, px + pw * 0.5f);
    float yb = fminf(ty + th * 0.5f, py + ph * 0.5f);
    bool valid = (xr >= xl) && (yb >= yt);
    float inter = (xr - xl) * (yb - yt);
    float uni = tw * th + pw * ph - inter;
    float safe = (uni == 0.0f) ? 1.0f : uni;
    return valid ? (inter / safe) : 0.0f;
}

__global__ __launch_bounds__(BLOCK) void yolo_loss_kernel(
    const float* __restrict__ pred, const float* __restrict__ targ,
    float* __restrict__ out) {
    // single buffer pair: 2 * 7680 B = 15360 B -> 10 blocks/CU
    __shared__ __align__(16) float sp[CELLS * DD];
    __shared__ __align__(16) float st[CELLS * DD];

    const int tid = threadIdx.x;
    const float4* gp = (const float4*)pred + (size_t)blockIdx.x * (ITERS * F4C);
    const float4* gt = (const float4*)targ + (size_t)blockIdx.x * (ITERS * F4C);
    float4* lp = (float4*)sp;
    float4* lt = (float4*)st;

    float4 rp[8], rt[8];
    // prologue: coalesced load of chunk 0 into registers
#pragma unroll
    for (int j = 0; j < 7; ++j) { rp[j] = gp[j * 64 + tid]; rt[j] = gt[j * 64 + tid]; }
    if (tid < 32) { rp[7] = gp[448 + tid]; rt[7] = gt[448 + tid]; }

    float acc = 0.0f;

#pragma unroll
    for (int it = 0; it < ITERS; ++it) {
        // ---- phase 1: regs -> LDS (vmcnt waits for chunk `it` happen here,
        // a full compute phase after issue in steady state) ----
        asm volatile("" ::: "memory");
#pragma unroll
        for (int j = 0; j < 7; ++j) { lp[j * 64 + tid] = rp[j]; lt[j * 64 + tid] = rt[j]; }
        if (tid < 32) { lp[448 + tid] = rp[7]; lt[448 + tid] = rt[7]; }
        asm volatile("" ::: "memory");

        // ---- phase 2: issue next chunk's loads; they fly during compute ----
        if (it + 1 < ITERS) {
            const float4* ngp = gp + (size_t)(it + 1) * F4C;
            const float4* ngt = gt + (size_t)(it + 1) * F4C;
#pragma unroll
            for (int j = 0; j < 7; ++j) { rp[j] = ngp[j * 64 + tid]; rt[j] = ngt[j * 64 + tid]; }
            if (tid < 32) { rp[7] = ngp[448 + tid]; rt[7] = ngt[448 + tid]; }
        }
        asm volatile("" ::: "memory");

        // ---- phase 3: per-cell loss from LDS (wave-private, HW in-order LDS
        // pipe + compiler fences give write->read ordering; no barrier) ----
        const float* p = &sp[tid * DD];
        const float* t = &st[tid * DD];

        float t4 = t[4];
        float obj = (t4 > 0.0f) ? 1.0f : 0.0f;
        float noobj = (t4 == 0.0f) ? 1.0f : 0.0f;

        float cls = 0.0f;
#pragma unroll
        for (int k = 10; k < 30; ++k) {
            float d = t[k] - p[k];
            cls += d * d;
        }
        cls *= obj;

        float d4 = t4 - p[4];
        float conf_noobj = noobj * d4 * d4;

        float tx = t[0], ty = t[1], tw = t[2], th = t[3];
        float iou1 = iou_t(tx, ty, tw, th, p[0], p[1], p[2], p[3]);
        float iou2 = iou_t(tx, ty, tw, th, p[5], p[6], p[7], p[8]);
        float resp1 = (iou1 > iou2) ? 1.0f : 0.0f;
        float m1 = obj * resp1;
        float m2 = obj * (1.0f - resp1);

        float e1 = iou1 - p[4];
        float e2 = iou2 - p[9];
        float conf_obj = m1 * e1 * e1 + m2 * e2 * e2;

        float dx1 = tx - p[0], dy1 = ty - p[1];
        float dx2 = tx - p[5], dy2 = ty - p[6];
        float xy = m1 * (dx1 * dx1 + dy1 * dy1) + m2 * (dx2 * dx2 + dy2 * dy2);

        float dw1 = tw - p[2], dh1 = th - p[3];
        float dw2 = tw - p[7], dh2 = th - p[8];
        float wh = m1 * (dw1 * dw1 + dh1 * dh1) + m2 * (dw2 * dw2 + dh2 * dh2);

        acc += LAMBDA_COORD * (xy + wh) + conf_obj + LAMBDA_NOOBJ * conf_noobj + cls;
    }

    // 64-lane wave reduction
#pragma unroll
    for (int off = 32; off > 0; off >>= 1) acc += __shfl_down(acc, off);
    if (tid == 0) atomicAdd(out, acc * (1.0f / 16384.0f));
}

extern "C" void kernel_launch(void* const* d_in, const int* in_sizes, int n_in,
                              void* d_out, int out_size, void* d_ws, size_t ws_size,
                              hipStream_t stream) {
    const float* pred = (const float*)d_in[0];  // y
    const float* targ = (const float*)d_in[1];  // gt
    float* out = (float*)d_out;

    hipMemsetAsync(out, 0, sizeof(float), stream);

    const int cells = in_sizes[0] / DD;          // 802816
    const int grid = cells / (CELLS * ITERS);    // 3136 (exact)
    yolo_loss_kernel<<<grid, BLOCK, 0, stream>>>(pred, targ, out);
}

// Round 4
// 206.290 us; speedup vs baseline: 1.1458x; 1.1458x over previous
//
#include <hip/hip_runtime.h>

#define LAMBDA_COORD 5.0f
#define LAMBDA_NOOBJ 0.5f
#define DD 30
#define BLOCK 256

__device__ __forceinline__ float iou_t(float tx, float ty, float tw, float th,
                                       float px, float py, float pw, float ph) {
    float xl = fmaxf(tx - tw * 0.5f, px - pw * 0.5f);
    float yt = fmaxf(ty - th * 0.5f, py - ph * 0.5f);
    float xr = fminf(tx + tw * 0.5f, px + pw * 0.5f);
    float yb = fminf(ty + th * 0.5f, py + ph * 0.5f);
    bool valid = (xr >= xl) && (yb >= yt);
    float inter = (xr - xl) * (yb - yt);
    float uni = tw * th + pw * ph - inter;
    float safe = (uni == 0.0f) ? 1.0f : uni;
    return valid ? (inter / safe) : 0.0f;
}

// element k of a float2[15] register array (k is a compile-time constant after unroll)
#define EL(A, k) (((k) & 1) ? A[(k) >> 1].y : A[(k) >> 1].x)

__global__ __launch_bounds__(BLOCK, 4) void yolo_loss_kernel(
    const float* __restrict__ pred, const float* __restrict__ targ,
    float* __restrict__ out) {
    __shared__ float wpart[BLOCK / 64];

    const int tid = threadIdx.x;
    const size_t cell = (size_t)blockIdx.x * BLOCK + tid;

    // ---- direct global -> register load: 15 x float2 per input, no LDS ----
    const float2* gp = (const float2*)(pred + cell * DD);
    const float2* gt = (const float2*)(targ + cell * DD);
    float2 P[15], T[15];
#pragma unroll
    for (int j = 0; j < 15; ++j) P[j] = gp[j];
#pragma unroll
    for (int j = 0; j < 15; ++j) T[j] = gt[j];

    // ---- per-cell loss, all from registers ----
    float t4 = EL(T, 4);
    float obj = (t4 > 0.0f) ? 1.0f : 0.0f;
    float noobj = (t4 == 0.0f) ? 1.0f : 0.0f;

    float cls = 0.0f;
#pragma unroll
    for (int j = 5; j < 15; ++j) {   // channels 10..29
        float dx = T[j].x - P[j].x;
        float dy = T[j].y - P[j].y;
        cls += dx * dx + dy * dy;
    }
    cls *= obj;

    float d4 = t4 - EL(P, 4);
    float conf_noobj = noobj * d4 * d4;

    float tx = EL(T, 0), ty = EL(T, 1), tw = EL(T, 2), th = EL(T, 3);
    float p0 = EL(P, 0), p1 = EL(P, 1), p2 = EL(P, 2), p3 = EL(P, 3);
    float p4 = EL(P, 4), p5 = EL(P, 5), p6 = EL(P, 6), p7 = EL(P, 7);
    float p8 = EL(P, 8), p9 = EL(P, 9);

    float iou1 = iou_t(tx, ty, tw, th, p0, p1, p2, p3);
    float iou2 = iou_t(tx, ty, tw, th, p5, p6, p7, p8);
    float resp1 = (iou1 > iou2) ? 1.0f : 0.0f;
    float m1 = obj * resp1;
    float m2 = obj * (1.0f - resp1);

    float e1 = iou1 - p4;
    float e2 = iou2 - p9;
    float conf_obj = m1 * e1 * e1 + m2 * e2 * e2;

    float dx1 = tx - p0, dy1 = ty - p1;
    float dx2 = tx - p5, dy2 = ty - p6;
    float xy = m1 * (dx1 * dx1 + dy1 * dy1) + m2 * (dx2 * dx2 + dy2 * dy2);

    float dw1 = tw - p2, dh1 = th - p3;
    float dw2 = tw - p7, dh2 = th - p8;
    float wh = m1 * (dw1 * dw1 + dh1 * dh1) + m2 * (dw2 * dw2 + dh2 * dh2);

    float loss = LAMBDA_COORD * (xy + wh) + conf_obj + LAMBDA_NOOBJ * conf_noobj + cls;

    // ---- 64-lane wave reduction, then block reduction, one atomic/block ----
#pragma unroll
    for (int off = 32; off > 0; off >>= 1) loss += __shfl_down(loss, off);
    if ((tid & 63) == 0) wpart[tid >> 6] = loss;
    __syncthreads();
    if (tid == 0) {
        float s = wpart[0] + wpart[1] + wpart[2] + wpart[3];
        atomicAdd(out, s * (1.0f / 16384.0f));
    }
}

extern "C" void kernel_launch(void* const* d_in, const int* in_sizes, int n_in,
                              void* d_out, int out_size, void* d_ws, size_t ws_size,
                              hipStream_t stream) {
    const float* pred = (const float*)d_in[0];  // y
    const float* targ = (const float*)d_in[1];  // gt
    float* out = (float*)d_out;

    hipMemsetAsync(out, 0, sizeof(float), stream);

    const int cells = in_sizes[0] / DD;   // 802816
    const int grid = cells / BLOCK;       // 3136 (exact)
    yolo_loss_kernel<<<grid, BLOCK, 0, stream>>>(pred, targ, out);
}